// Round 1
// baseline (561.370 us; speedup 1.0000x reference)
//
#include <hip/hip_runtime.h>
#include <math.h>

#define NC 1024
#define HID 256
#define NI 2

// ---------------------------------------------------------------------------
// Top-K gating: rank = #{j : |g_j|>|g_e| or (|g_j|==|g_e| and j<e)}; keep rank<K.
// Matches jax.lax.top_k (descending, ties by lower index).
// Output compact: gidx/gval[(level*2+img)*256 + rank]
// ---------------------------------------------------------------------------
__global__ __launch_bounds__(256) void gate_kernel(const float* __restrict__ rg,
                                                   int* __restrict__ gidx,
                                                   float* __restrict__ gval)
{
    const int EDAT[5] = {8, 16, 64, 256, 1024};
    const int KDAT[5] = {4, 4, 32, 32, 256};
    const int OFF[5]  = {0, 8, 24, 88, 344};
    const int level = blockIdx.x, img = blockIdx.y;
    const int E = EDAT[level], K = KDAT[level], off = OFF[level];
    __shared__ float g[1024];
    const float* src = rg + img * 1368 + off;
    for (int e = threadIdx.x; e < E; e += 256) g[e] = src[e];
    __syncthreads();
    for (int e = threadIdx.x; e < E; e += 256) {
        float a = fabsf(g[e]);
        int rank = 0;
        for (int j = 0; j < E; j++) {
            float aj = fabsf(g[j]);
            rank += (aj > a) || (aj == a && j < e);
        }
        if (rank < K) {
            int base = (level * 2 + img) * 256;
            gidx[base + rank] = e;
            gval[base + rank] = g[e];
        }
    }
}

// ---------------------------------------------------------------------------
// Layer 0: x[i,c,h] = sum_k gv[k] * sin(30*(coords[c]·W0[h*8+gi[k]] + b0[...]))
// ---------------------------------------------------------------------------
__global__ __launch_bounds__(256) void layer0_kernel(const float* __restrict__ coords,
                                                     const float* __restrict__ W0,
                                                     const float* __restrict__ b0,
                                                     const int* __restrict__ gidx,
                                                     const float* __restrict__ gval,
                                                     float* __restrict__ xout)
{
    const int c = blockIdx.x, img = blockIdx.y, h = threadIdx.x;
    __shared__ int gi[4];
    __shared__ float gv[4];
    if (h < 4) {
        int base = (0 * 2 + img) * 256;
        gi[h] = gidx[base + h];
        gv[h] = gval[base + h];
    }
    __syncthreads();
    const float c0 = coords[c * 2], c1 = coords[c * 2 + 1];
    float s = 0.f;
#pragma unroll
    for (int k = 0; k < 4; k++) {
        int row = h * 8 + gi[k];
        s += gv[k] * sinf(30.f * (c0 * W0[row * 2] + c1 * W0[row * 2 + 1] + b0[row]));
    }
    xout[((size_t)img * NC + c) * HID + h] = s;
}

// ---------------------------------------------------------------------------
// Mid layers 1..3: fused gathered-row GEMM + sin + gate-weighted reduce.
// Rows packed r = dd*K + k (R = 256*K). Block tile: 64 coords x 64 rows,
// thread 4x4, 256 threads. LDS staged transposed [kk][m], stride 68 (16B align).
// K==4: thread's 4 rows = one full dd group (direct write).
// K==32: 8-thread LDS reduce per dd group.
// ---------------------------------------------------------------------------
template <int E, int K>
__global__ __launch_bounds__(256) void layer_mid_kernel(const float* __restrict__ x_in,
                                                        const float* __restrict__ W,
                                                        const float* __restrict__ bias,
                                                        const int* __restrict__ gidx,
                                                        const float* __restrict__ gval,
                                                        const int level,
                                                        float* __restrict__ x_out)
{
    const int img = blockIdx.z;
    const int c0 = blockIdx.x * 64;
    const int r0 = blockIdx.y * 64;
    const int tid = threadIdx.x;
    const int tm = tid & 15, tn = tid >> 4;

    __shared__ float As[32][68];
    __shared__ float Bs[32][68];
    __shared__ float gvS[64], biasS[64];
    __shared__ int wrowS[64];
    __shared__ float red[64][17];

    if (tid < 64) {
        int rg = r0 + tid;
        int dd = rg / K, k = rg % K;
        int base = (level * 2 + img) * 256;
        int e = gidx[base + k];
        int wrow = dd * E + e;
        wrowS[tid] = wrow;
        gvS[tid] = gval[base + k];
        biasS[tid] = bias[wrow];
    }

    float acc[4][4];
#pragma unroll
    for (int i = 0; i < 4; i++)
#pragma unroll
        for (int j = 0; j < 4; j++) acc[i][j] = 0.f;

    const float* xbase = x_in + (size_t)img * NC * HID;

    for (int kc = 0; kc < 256; kc += 32) {
        __syncthreads();  // protects prev iter reads + wrowS setup (first iter)
#pragma unroll
        for (int q = 0; q < 2; q++) {
            int f = tid * 2 + q;
            int m = f >> 3, kb = f & 7;
            const float4 av = *(const float4*)(xbase + (size_t)(c0 + m) * HID + kc + kb * 4);
            As[kb * 4 + 0][m] = av.x;
            As[kb * 4 + 1][m] = av.y;
            As[kb * 4 + 2][m] = av.z;
            As[kb * 4 + 3][m] = av.w;
            const float4 bv = *(const float4*)(W + (size_t)wrowS[m] * HID + kc + kb * 4);
            Bs[kb * 4 + 0][m] = bv.x;
            Bs[kb * 4 + 1][m] = bv.y;
            Bs[kb * 4 + 2][m] = bv.z;
            Bs[kb * 4 + 3][m] = bv.w;
        }
        __syncthreads();
#pragma unroll 8
        for (int kk = 0; kk < 32; kk++) {
            const float4 a4 = *(const float4*)&As[kk][tm * 4];
            const float4 b4 = *(const float4*)&Bs[kk][tn * 4];
            float a[4] = {a4.x, a4.y, a4.z, a4.w};
            float b[4] = {b4.x, b4.y, b4.z, b4.w};
#pragma unroll
            for (int i = 0; i < 4; i++)
#pragma unroll
                for (int j = 0; j < 4; j++) acc[i][j] = fmaf(a[i], b[j], acc[i][j]);
        }
    }

    // epilogue: sin + gate weight + expert-group reduce
    if constexpr (K == 4) {
#pragma unroll
        for (int mi = 0; mi < 4; mi++) {
            float s = 0.f;
#pragma unroll
            for (int ni = 0; ni < 4; ni++) {
                int n = tn * 4 + ni;
                s += gvS[n] * sinf(30.f * (acc[mi][ni] + biasS[n]));
            }
            int dd = r0 / 4 + tn;
            x_out[((size_t)img * NC + (c0 + tm * 4 + mi)) * HID + dd] = s;
        }
    } else {
#pragma unroll
        for (int mi = 0; mi < 4; mi++) {
            float s = 0.f;
#pragma unroll
            for (int ni = 0; ni < 4; ni++) {
                int n = tn * 4 + ni;
                s += gvS[n] * sinf(30.f * (acc[mi][ni] + biasS[n]));
            }
            red[tm * 4 + mi][tn] = s;
        }
        __syncthreads();
        if (tid < 128) {
            int c = tid >> 1, gg = tid & 1;
            float s = 0.f;
#pragma unroll
            for (int t = 0; t < 8; t++) s += red[c][gg * 8 + t];
            int dd = r0 / 32 + gg;
            x_out[((size_t)img * NC + (c0 + c)) * HID + dd] = s;
        }
    }
}

// ---------------------------------------------------------------------------
// Layer 4 (output): out[i,c,d] = sum_e gv[e]*(W4[d*1024+e,:]·x[i,c,:] + b4[...])
// One expert per thread (K=256), 8-coord tile, block shuffle-reduce.
// ---------------------------------------------------------------------------
__global__ __launch_bounds__(256) void layer4_kernel(const float* __restrict__ x_in,
                                                     const float* __restrict__ W4,
                                                     const float* __restrict__ b4,
                                                     const int* __restrict__ gidx,
                                                     const float* __restrict__ gval,
                                                     float* __restrict__ out)
{
    const int img = blockIdx.y;
    const int c0 = blockIdx.x * 8;
    const int t = threadIdx.x;
    __shared__ float xs[8][256];
    __shared__ float redl[4][24];
    const int base = (4 * 2 + img) * 256;
    const int e = gidx[base + t];
    const float g = gval[base + t];

    const float* xb = x_in + ((size_t)img * NC + c0) * HID;
#pragma unroll
    for (int q = 0; q < 2; q++) {
        int f = t + q * 256;
        int c = f >> 6, j4 = f & 63;
        *(float4*)&xs[c][j4 * 4] = *(const float4*)(xb + c * HID + j4 * 4);
    }
    __syncthreads();

    float acc[3][8];
#pragma unroll
    for (int d = 0; d < 3; d++)
#pragma unroll
        for (int c = 0; c < 8; c++) acc[d][c] = 0.f;

    const float* w0p = W4 + (size_t)(0 * 1024 + e) * 256;
    const float* w1p = W4 + (size_t)(1 * 1024 + e) * 256;
    const float* w2p = W4 + (size_t)(2 * 1024 + e) * 256;
#pragma unroll 2
    for (int j = 0; j < 256; j += 4) {
        const float4 w0 = *(const float4*)(w0p + j);
        const float4 w1 = *(const float4*)(w1p + j);
        const float4 w2 = *(const float4*)(w2p + j);
#pragma unroll
        for (int c = 0; c < 8; c++) {
            const float4 xv = *(const float4*)&xs[c][j];
            acc[0][c] += w0.x * xv.x + w0.y * xv.y + w0.z * xv.z + w0.w * xv.w;
            acc[1][c] += w1.x * xv.x + w1.y * xv.y + w1.z * xv.z + w1.w * xv.w;
            acc[2][c] += w2.x * xv.x + w2.y * xv.y + w2.z * xv.z + w2.w * xv.w;
        }
    }

    float p[24];
#pragma unroll
    for (int d = 0; d < 3; d++) {
        const float bb = b4[d * 1024 + e];
#pragma unroll
        for (int c = 0; c < 8; c++) p[d * 8 + c] = g * (acc[d][c] + bb);
    }
#pragma unroll
    for (int v = 0; v < 24; v++) {
        float x = p[v];
#pragma unroll
        for (int off = 32; off; off >>= 1) x += __shfl_down(x, off);
        p[v] = x;
    }
    if ((t & 63) == 0) {
        int w = t >> 6;
#pragma unroll
        for (int v = 0; v < 24; v++) redl[w][v] = p[v];
    }
    __syncthreads();
    if (t < 24) {
        float s = redl[0][t] + redl[1][t] + redl[2][t] + redl[3][t];
        int d = t / 8, c = t % 8;
        out[((size_t)img * NC + c0 + c) * 3 + d] = s;
    }
}

// ---------------------------------------------------------------------------
extern "C" void kernel_launch(void* const* d_in, const int* in_sizes, int n_in,
                              void* d_out, int out_size, void* d_ws, size_t ws_size,
                              hipStream_t stream)
{
    const float* rg     = (const float*)d_in[0];
    const float* coords = (const float*)d_in[1];
    const float* W0 = (const float*)d_in[2];
    const float* b0 = (const float*)d_in[3];
    const float* W1 = (const float*)d_in[4];
    const float* b1 = (const float*)d_in[5];
    const float* W2 = (const float*)d_in[6];
    const float* b2 = (const float*)d_in[7];
    const float* W3 = (const float*)d_in[8];
    const float* b3 = (const float*)d_in[9];
    const float* W4 = (const float*)d_in[10];
    const float* b4 = (const float*)d_in[11];
    float* out = (float*)d_out;

    char* ws = (char*)d_ws;
    int* gidx  = (int*)ws;                       // 5*2*256 ints   = 10240 B
    float* gval = (float*)(ws + 10240);          // 5*2*256 floats = 10240 B
    float* xA = (float*)(ws + 20480);            // 2*1024*256 f32 = 2 MiB
    float* xB = xA + (size_t)NI * NC * HID;      // 2 MiB

    gate_kernel<<<dim3(5, 2), 256, 0, stream>>>(rg, gidx, gval);
    layer0_kernel<<<dim3(NC, NI), 256, 0, stream>>>(coords, W0, b0, gidx, gval, xA);
    layer_mid_kernel<16, 4><<<dim3(16, 16, NI), 256, 0, stream>>>(xA, W1, b1, gidx, gval, 1, xB);
    layer_mid_kernel<64, 32><<<dim3(16, 128, NI), 256, 0, stream>>>(xB, W2, b2, gidx, gval, 2, xA);
    layer_mid_kernel<256, 32><<<dim3(16, 128, NI), 256, 0, stream>>>(xA, W3, b3, gidx, gval, 3, xB);
    layer4_kernel<<<dim3(128, NI), 256, 0, stream>>>(xB, W4, b4, gidx, gval, out);
}

// Round 3
// 448.686 us; speedup vs baseline: 1.2511x; 1.2511x over previous
//
#include <hip/hip_runtime.h>
#include <math.h>

#define NC 1024
#define HID 256
#define NI 2

typedef _Float16 f16x8 __attribute__((ext_vector_type(8)));
typedef float f32x4 __attribute__((ext_vector_type(4)));
using gvoid = __attribute__((address_space(1))) const void;
using lvoid = __attribute__((address_space(3))) void;

#define LO_SCALE 2048.0f
#define LO_INV (1.0f / 2048.0f)

// ---------------------------------------------------------------------------
// Top-K gating (matches jax.lax.top_k tie-breaking: desc, ties by low index).
// ---------------------------------------------------------------------------
__global__ __launch_bounds__(256) void gate_kernel(const float* __restrict__ rg,
                                                   int* __restrict__ gidx,
                                                   float* __restrict__ gval)
{
    const int EDAT[5] = {8, 16, 64, 256, 1024};
    const int KDAT[5] = {4, 4, 32, 32, 256};
    const int OFF[5]  = {0, 8, 24, 88, 344};
    const int level = blockIdx.x, img = blockIdx.y;
    const int E = EDAT[level], K = KDAT[level], off = OFF[level];
    __shared__ float g[1024];
    const float* src = rg + img * 1368 + off;
    for (int e = threadIdx.x; e < E; e += 256) g[e] = src[e];
    __syncthreads();
    for (int e = threadIdx.x; e < E; e += 256) {
        float a = fabsf(g[e]);
        int rank = 0;
        for (int j = 0; j < E; j++) {
            float aj = fabsf(g[j]);
            rank += (aj > a) || (aj == a && j < e);
        }
        if (rank < K) {
            int base = (level * 2 + img) * 256;
            gidx[base + rank] = e;
            gval[base + rank] = g[e];
        }
    }
}

// ---------------------------------------------------------------------------
// Layer 0: x[i,c,h] = sum_k gv[k]*sin(30*(coords[c]·W0row + b0))
// ---------------------------------------------------------------------------
__global__ __launch_bounds__(256) void layer0_kernel(const float* __restrict__ coords,
                                                     const float* __restrict__ W0,
                                                     const float* __restrict__ b0,
                                                     const int* __restrict__ gidx,
                                                     const float* __restrict__ gval,
                                                     float* __restrict__ xout)
{
    const int c = blockIdx.x, img = blockIdx.y, h = threadIdx.x;
    __shared__ int gi[4];
    __shared__ float gv[4];
    if (h < 4) {
        int base = (0 * 2 + img) * 256;
        gi[h] = gidx[base + h];
        gv[h] = gval[base + h];
    }
    __syncthreads();
    const float c0 = coords[c * 2], c1 = coords[c * 2 + 1];
    float s = 0.f;
#pragma unroll
    for (int k = 0; k < 4; k++) {
        int row = h * 8 + gi[k];
        s += gv[k] * sinf(30.f * (c0 * W0[row * 2] + c1 * W0[row * 2 + 1] + b0[row]));
    }
    xout[((size_t)img * NC + c) * HID + h] = s;
}

// ---------------------------------------------------------------------------
// x-pack: f32 x[img][1024][256] -> Ap f16 tiles [img][16 mtiles][8 chunks][64x64 swz]
// chunks 0-3 = hi(k=ch*64+c), 4-7 = lo*2048. Swizzle idx = r*64 + (c ^ ((r&7)<<3)).
// ---------------------------------------------------------------------------
__global__ __launch_bounds__(256) void xpack_kernel(const float* __restrict__ x,
                                                    _Float16* __restrict__ Ap)
{
    const int mt = blockIdx.x, img = blockIdx.y, ch = blockIdx.z;
    const int t = threadIdx.x;
    const int c = t & 63, r0 = t >> 6;
    const float* xb = x + ((size_t)img * NC + mt * 64) * HID;
    _Float16* ap = Ap + ((size_t)(img * 16 + mt) * 8 + ch) * 4096;
    const int kk = (ch & 3) * 64 + c;
    const bool lo = ch >= 4;
#pragma unroll
    for (int rr = 0; rr < 64; rr += 4) {
        int r = rr + r0;
        float v = xb[r * HID + kk];
        _Float16 h = (_Float16)v;
        _Float16 ov = lo ? (_Float16)((v - (float)h) * LO_SCALE) : h;
        ap[r * 64 + (c ^ ((r & 7) << 3))] = ov;
    }
}

// ---------------------------------------------------------------------------
// W-pack: gather active rows (per img), f16 hi / scaled-lo, pre-swizzled tiles.
// Bp layout [img][ntile(64 rows)][8 chunks][4096]. chunks 0-3 hi, 4-7 lo*2048.
// Also emits biasP[img][n], gvP[img][n] (ch==0 blocks).
// ---------------------------------------------------------------------------
__global__ __launch_bounds__(256) void wpack_kernel(const float* __restrict__ W,
                                                    const float* __restrict__ bias,
                                                    const int* __restrict__ gidx,
                                                    const float* __restrict__ gval,
                                                    int level, int E, int lgK,
                                                    _Float16* __restrict__ Bp,
                                                    float* __restrict__ biasP,
                                                    float* __restrict__ gvP,
                                                    int ntiles)
{
    const int ntile = blockIdx.x, img = blockIdx.y, ch = blockIdx.z;
    const int t = threadIdx.x;
    const int N = ntiles * 64;
    __shared__ int wrowS[64];
    const int base = (level * 2 + img) * 256;
    if (t < 64) {
        int n = ntile * 64 + t;
        int dd = n >> lgK, k = n & ((1 << lgK) - 1);
        int wrow = dd * E + gidx[base + k];
        wrowS[t] = wrow;
        if (ch == 0) {
            biasP[img * N + n] = bias[wrow];
            gvP[img * N + n] = gval[base + k];
        }
    }
    __syncthreads();
    const int c = t & 63, r0 = t >> 6;
    const int kk = (ch & 3) * 64 + c;
    const bool lo = ch >= 4;
    _Float16* bp = Bp + ((size_t)(img * ntiles + ntile) * 8 + ch) * 4096;
#pragma unroll
    for (int rr = 0; rr < 64; rr += 4) {
        int r = rr + r0;
        float v = W[(size_t)wrowS[r] * HID + kk];
        _Float16 h = (_Float16)v;
        _Float16 ov = lo ? (_Float16)((v - (float)h) * LO_SCALE) : h;
        bp[r * 64 + (c ^ ((r & 7) << 3))] = ov;
    }
}

// ---------------------------------------------------------------------------
// Mid-layer MFMA GEMM, split-f16 K'=768 (12 logical chunks over 8 stored):
//   acc  += hiA*hiB (ch 0-3)
//   accL += hiA*loB' (ch 4-7) + loA'*hiB (ch 8-11)   [lo' = lo*2048]
//   result = acc + accL/2048
// Tile 64m x 128n, 4 waves (2m x 2n), wave = 32x64 = 2x4 frags of 16x16x32.
// global_load_lds staging (linear dest, pre-swizzled source), swizzled ds_read.
// Epilogue: sin(30*(val+bias))*gv -> S[64][129] -> group reduce -> x_out.
// ---------------------------------------------------------------------------
template <int KGRP>
__global__ __launch_bounds__(256) void mid_mfma_kernel(const _Float16* __restrict__ Ap,
                                                       const _Float16* __restrict__ Bp,
                                                       const float* __restrict__ biasP,
                                                       const float* __restrict__ gvP,
                                                       float* __restrict__ x_out)
{
    const int mt = blockIdx.x, nt = blockIdx.y, img = blockIdx.z;
    const int tid = threadIdx.x;
    const int wave = tid >> 6, lane = tid & 63;
    const int wm = wave & 1, wn = wave >> 1;
    const int l15 = lane & 15, lhi = lane >> 4;

    __shared__ __align__(16) char lds[33088];  // staging 24KB; epilogue S 64x129 f32
    float* S = (float*)lds;

    const int ntiles = gridDim.y * 2;  // N/64
    const int N = ntiles * 64;
    const _Float16* ag = Ap + ((size_t)(img * 16 + mt) * 8) * 4096;
    const _Float16* bg = Bp + ((size_t)(img * ntiles + nt * 2) * 8) * 4096;

    f32x4 acc[2][4], accL[2][4];
#pragma unroll
    for (int mi = 0; mi < 2; mi++)
#pragma unroll
        for (int ni = 0; ni < 4; ni++) { acc[mi][ni] = (f32x4)0.f; accL[mi][ni] = (f32x4)0.f; }

    for (int ch = 0; ch < 12; ++ch) {
        const int sa = (ch < 8) ? (ch & 3) : (ch - 4);  // A: hi,hi,lo'
        const int sb = (ch < 8) ? ch : (ch - 8);        // B: hi,lo',hi
        __syncthreads();
        const _Float16* gaw = ag + sa * 4096;
#pragma unroll
        for (int q = 0; q < 6; ++q) {
            int s = wave * 6 + q;
            const _Float16* g;
            if (s < 8) {
                g = gaw + s * 512 + lane * 8;
            } else {
                int s8 = s - 8;
                g = bg + ((size_t)((s8 >> 3) * 8 + sb)) * 4096 + (s8 & 7) * 512 + lane * 8;
            }
            __builtin_amdgcn_global_load_lds((gvoid*)g, (lvoid*)(lds + s * 1024), 16, 0, 0);
        }
        asm volatile("s_waitcnt vmcnt(0)" ::: "memory");
        __syncthreads();

        f16x8 af[2][2], bf[2][4];
#pragma unroll
        for (int ks = 0; ks < 2; ++ks) {
#pragma unroll
            for (int mi = 0; mi < 2; ++mi) {
                int row = wm * 32 + mi * 16 + l15;
                int slot = (lhi + 4 * ks) ^ (row & 7);
                af[ks][mi] = *(const f16x8*)(lds + row * 128 + slot * 16);
            }
#pragma unroll
            for (int ni = 0; ni < 4; ++ni) {
                int row = wn * 64 + ni * 16 + l15;
                int slot = (lhi + 4 * ks) ^ (row & 7);
                bf[ks][ni] = *(const f16x8*)(lds + 8192 + row * 128 + slot * 16);
            }
        }
        if (ch < 4) {
#pragma unroll
            for (int ks = 0; ks < 2; ++ks)
#pragma unroll
                for (int mi = 0; mi < 2; ++mi)
#pragma unroll
                    for (int ni = 0; ni < 4; ++ni)
                        acc[mi][ni] = __builtin_amdgcn_mfma_f32_16x16x32_f16(af[ks][mi], bf[ks][ni],
                                                                             acc[mi][ni], 0, 0, 0);
        } else {
#pragma unroll
            for (int ks = 0; ks < 2; ++ks)
#pragma unroll
                for (int mi = 0; mi < 2; ++mi)
#pragma unroll
                    for (int ni = 0; ni < 4; ++ni)
                        accL[mi][ni] = __builtin_amdgcn_mfma_f32_16x16x32_f16(af[ks][mi], bf[ks][ni],
                                                                              accL[mi][ni], 0, 0, 0);
        }
    }
    __syncthreads();

    // epilogue: combine hi/lo accumulators, sin + gate weight -> S
#pragma unroll
    for (int mi = 0; mi < 2; ++mi)
#pragma unroll
        for (int ni = 0; ni < 4; ++ni) {
            int n = wn * 64 + ni * 16 + l15;
            int gn = nt * 128 + n;
            float bv = biasP[img * N + gn];
            float gv = gvP[img * N + gn];
#pragma unroll
            for (int r = 0; r < 4; ++r) {
                int m = wm * 32 + mi * 16 + lhi * 4 + r;
                float val = acc[mi][ni][r] + accL[mi][ni][r] * LO_INV;
                S[m * 129 + n] = gv * sinf(30.f * (val + bv));
            }
        }
    __syncthreads();

    float* xo = x_out + ((size_t)img * NC + mt * 64) * HID;
    if (KGRP == 32) {
        int m = tid >> 2, d = tid & 3;
        float s = 0.f;
#pragma unroll
        for (int j = 0; j < 32; ++j) s += S[m * 129 + d * 32 + ((j + d * 8) & 31)];
        xo[m * HID + nt * 4 + d] = s;
    } else {
#pragma unroll
        for (int rep = 0; rep < 8; ++rep) {
            int idx = rep * 256 + tid;
            int m = idx >> 5, d = idx & 31;
            const float* Sp = S + m * 129 + d * 4;
            xo[m * HID + nt * 32 + d] = Sp[0] + Sp[1] + Sp[2] + Sp[3];
        }
    }
}

// ---------------------------------------------------------------------------
// Layer 4 (output): out[i,c,d] = sum_e gv[e]*(W4[d*1024+e,:]·x[i,c,:] + b4)
// ---------------------------------------------------------------------------
__global__ __launch_bounds__(256) void layer4_kernel(const float* __restrict__ x_in,
                                                     const float* __restrict__ W4,
                                                     const float* __restrict__ b4,
                                                     const int* __restrict__ gidx,
                                                     const float* __restrict__ gval,
                                                     float* __restrict__ out)
{
    const int img = blockIdx.y;
    const int c0 = blockIdx.x * 8;
    const int t = threadIdx.x;
    __shared__ float xs[8][256];
    __shared__ float redl[4][24];
    const int base = (4 * 2 + img) * 256;
    const int e = gidx[base + t];
    const float g = gval[base + t];

    const float* xb = x_in + ((size_t)img * NC + c0) * HID;
#pragma unroll
    for (int q = 0; q < 2; q++) {
        int f = t + q * 256;
        int c = f >> 6, j4 = f & 63;
        *(float4*)&xs[c][j4 * 4] = *(const float4*)(xb + c * HID + j4 * 4);
    }
    __syncthreads();

    float acc[3][8];
#pragma unroll
    for (int d = 0; d < 3; d++)
#pragma unroll
        for (int c = 0; c < 8; c++) acc[d][c] = 0.f;

    const float* w0p = W4 + (size_t)(0 * 1024 + e) * 256;
    const float* w1p = W4 + (size_t)(1 * 1024 + e) * 256;
    const float* w2p = W4 + (size_t)(2 * 1024 + e) * 256;
#pragma unroll 2
    for (int j = 0; j < 256; j += 4) {
        const float4 w0 = *(const float4*)(w0p + j);
        const float4 w1 = *(const float4*)(w1p + j);
        const float4 w2 = *(const float4*)(w2p + j);
#pragma unroll
        for (int c = 0; c < 8; c++) {
            const float4 xv = *(const float4*)&xs[c][j];
            acc[0][c] += w0.x * xv.x + w0.y * xv.y + w0.z * xv.z + w0.w * xv.w;
            acc[1][c] += w1.x * xv.x + w1.y * xv.y + w1.z * xv.z + w1.w * xv.w;
            acc[2][c] += w2.x * xv.x + w2.y * xv.y + w2.z * xv.z + w2.w * xv.w;
        }
    }

    float p[24];
#pragma unroll
    for (int d = 0; d < 3; d++) {
        const float bb = b4[d * 1024 + e];
#pragma unroll
        for (int c = 0; c < 8; c++) p[d * 8 + c] = g * (acc[d][c] + bb);
    }
#pragma unroll
    for (int v = 0; v < 24; v++) {
        float x = p[v];
#pragma unroll
        for (int off = 32; off; off >>= 1) x += __shfl_down(x, off);
        p[v] = x;
    }
    if ((t & 63) == 0) {
        int w = t >> 6;
#pragma unroll
        for (int v = 0; v < 24; v++) redl[w][v] = p[v];
    }
    __syncthreads();
    if (t < 24) {
        float s = redl[0][t] + redl[1][t] + redl[2][t] + redl[3][t];
        int d = t / 8, c = t % 8;
        out[((size_t)img * NC + c0 + c) * 3 + d] = s;
    }
}

// ---------------------------------------------------------------------------
extern "C" void kernel_launch(void* const* d_in, const int* in_sizes, int n_in,
                              void* d_out, int out_size, void* d_ws, size_t ws_size,
                              hipStream_t stream)
{
    const float* rg     = (const float*)d_in[0];
    const float* coords = (const float*)d_in[1];
    const float* W0 = (const float*)d_in[2];
    const float* b0 = (const float*)d_in[3];
    const float* W1 = (const float*)d_in[4];
    const float* b1 = (const float*)d_in[5];
    const float* W2 = (const float*)d_in[6];
    const float* b2 = (const float*)d_in[7];
    const float* W3 = (const float*)d_in[8];
    const float* b3 = (const float*)d_in[9];
    const float* W4 = (const float*)d_in[10];
    const float* b4 = (const float*)d_in[11];
    float* out = (float*)d_out;

    char* ws = (char*)d_ws;
    int*      gidx  = (int*)ws;                                // 10240 B
    float*    gval  = (float*)(ws + 10240);                    // 10240 B
    float*    xA    = (float*)(ws + 20480);                    // 2 MiB
    float*    xB    = (float*)(ws + 2117632);                  // 2 MiB
    _Float16* Ap    = (_Float16*)(ws + 4214784);               // 2 MiB
    _Float16* Bp    = (_Float16*)(ws + 6311936);               // 16 MiB
    float*    biasP = (float*)(ws + 23089152);                 // 64 KiB
    float*    gvP   = (float*)(ws + 23154688);                 // 64 KiB

    gate_kernel<<<dim3(5, 2), 256, 0, stream>>>(rg, gidx, gval);
    layer0_kernel<<<dim3(NC, NI), 256, 0, stream>>>(coords, W0, b0, gidx, gval, xA);

    // level 1: E=16, K=4, N=1024
    xpack_kernel<<<dim3(16, 2, 8), 256, 0, stream>>>(xA, Ap);
    wpack_kernel<<<dim3(16, 2, 8), 256, 0, stream>>>(W1, b1, gidx, gval, 1, 16, 2, Bp, biasP, gvP, 16);
    mid_mfma_kernel<4><<<dim3(16, 8, 2), 256, 0, stream>>>(Ap, Bp, biasP, gvP, xB);

    // level 2: E=64, K=32, N=8192
    xpack_kernel<<<dim3(16, 2, 8), 256, 0, stream>>>(xB, Ap);
    wpack_kernel<<<dim3(128, 2, 8), 256, 0, stream>>>(W2, b2, gidx, gval, 2, 64, 5, Bp, biasP, gvP, 128);
    mid_mfma_kernel<32><<<dim3(16, 64, 2), 256, 0, stream>>>(Ap, Bp, biasP, gvP, xA);

    // level 3: E=256, K=32, N=8192
    xpack_kernel<<<dim3(16, 2, 8), 256, 0, stream>>>(xA, Ap);
    wpack_kernel<<<dim3(128, 2, 8), 256, 0, stream>>>(W3, b3, gidx, gval, 3, 256, 5, Bp, biasP, gvP, 128);
    mid_mfma_kernel<32><<<dim3(16, 64, 2), 256, 0, stream>>>(Ap, Bp, biasP, gvP, xB);

    layer4_kernel<<<dim3(128, NI), 256, 0, stream>>>(xB, W4, b4, gidx, gval, out);
}

// Round 5
// 405.550 us; speedup vs baseline: 1.3842x; 1.1064x over previous
//
#include <hip/hip_runtime.h>
#include <math.h>

#define NC 1024
#define HID 256
#define NI 2

typedef _Float16 f16x8 __attribute__((ext_vector_type(8)));
typedef float f32x4 __attribute__((ext_vector_type(4)));
using gvoid = __attribute__((address_space(1))) const void;
using lvoid = __attribute__((address_space(3))) void;

#define LO_SCALE 2048.0f
#define LO_INV (1.0f / 2048.0f)

// ---------------------------------------------------------------------------
// Top-K gating, thread-per-element (block=1024). rank = #{j : |g_j|>|g_e| or
// (|g_j|==|g_e| and j<e)}; keep rank<K. Matches jax.lax.top_k ordering.
// ---------------------------------------------------------------------------
__global__ __launch_bounds__(1024) void gate_kernel(const float* __restrict__ rg,
                                                    int* __restrict__ gidx,
                                                    float* __restrict__ gval)
{
    const int EDAT[5] = {8, 16, 64, 256, 1024};
    const int KDAT[5] = {4, 4, 32, 32, 256};
    const int OFF[5]  = {0, 8, 24, 88, 344};
    const int level = blockIdx.x, img = blockIdx.y;
    const int E = EDAT[level], K = KDAT[level], off = OFF[level];
    __shared__ float ga[1024];
    const float* src = rg + img * 1368 + off;
    const int t = threadIdx.x;
    if (t < E) ga[t] = src[t];
    __syncthreads();
    if (t < E) {
        const float v = ga[t];
        const float a = fabsf(v);
        int rank = 0;
#pragma unroll 8
        for (int j = 0; j < E; j++) {
            float aj = fabsf(ga[j]);
            rank += (aj > a) || (aj == a && j < t);
        }
        if (rank < K) {
            int base = (level * 2 + img) * 256;
            gidx[base + rank] = t;
            gval[base + rank] = v;
        }
    }
}

// ---------------------------------------------------------------------------
// Layer 0: x[i,c,h] = sum_k gv[k]*sin(30*(coords[c]·W0row + b0))
// ---------------------------------------------------------------------------
__global__ __launch_bounds__(256) void layer0_kernel(const float* __restrict__ coords,
                                                     const float* __restrict__ W0,
                                                     const float* __restrict__ b0,
                                                     const int* __restrict__ gidx,
                                                     const float* __restrict__ gval,
                                                     float* __restrict__ xout)
{
    const int c = blockIdx.x, img = blockIdx.y, h = threadIdx.x;
    __shared__ int gi[4];
    __shared__ float gv[4];
    if (h < 4) {
        int base = (0 * 2 + img) * 256;
        gi[h] = gidx[base + h];
        gv[h] = gval[base + h];
    }
    __syncthreads();
    const float c0 = coords[c * 2], c1 = coords[c * 2 + 1];
    float s = 0.f;
#pragma unroll
    for (int k = 0; k < 4; k++) {
        int row = h * 8 + gi[k];
        s += gv[k] * sinf(30.f * (c0 * W0[row * 2] + c1 * W0[row * 2 + 1] + b0[row]));
    }
    xout[((size_t)img * NC + c) * HID + h] = s;
}

// ---------------------------------------------------------------------------
// x-pack: f32 x[img][1024][256] -> Ap f16 tiles [img][16 mtiles][8 chunks][64x64 swz]
// chunks 0-3 = hi(k=ch*64+c), 4-7 = lo*2048. Swizzle idx = r*64 + (c ^ ((r&7)<<3)).
// ---------------------------------------------------------------------------
__global__ __launch_bounds__(256) void xpack_kernel(const float* __restrict__ x,
                                                    _Float16* __restrict__ Ap)
{
    const int mt = blockIdx.x, img = blockIdx.y, ch = blockIdx.z;
    const int t = threadIdx.x;
    const int c = t & 63, r0 = t >> 6;
    const float* xb = x + ((size_t)img * NC + mt * 64) * HID;
    _Float16* ap = Ap + ((size_t)(img * 16 + mt) * 8 + ch) * 4096;
    const int kk = (ch & 3) * 64 + c;
    const bool lo = ch >= 4;
#pragma unroll
    for (int rr = 0; rr < 64; rr += 4) {
        int r = rr + r0;
        float v = xb[r * HID + kk];
        _Float16 h = (_Float16)v;
        _Float16 ov = lo ? (_Float16)((v - (float)h) * LO_SCALE) : h;
        ap[r * 64 + (c ^ ((r & 7) << 3))] = ov;
    }
}

// ---------------------------------------------------------------------------
// W-pack: gather active rows (per img), f16 hi / scaled-lo, pre-swizzled tiles.
// Bp layout [img][ntile(64 rows)][8 chunks][4096]. chunks 0-3 hi, 4-7 lo*2048.
// Also emits biasP[img][n], gvP[img][n] (ch==0 blocks).
// ---------------------------------------------------------------------------
__global__ __launch_bounds__(256) void wpack_kernel(const float* __restrict__ W,
                                                    const float* __restrict__ bias,
                                                    const int* __restrict__ gidx,
                                                    const float* __restrict__ gval,
                                                    int level, int E, int lgK,
                                                    _Float16* __restrict__ Bp,
                                                    float* __restrict__ biasP,
                                                    float* __restrict__ gvP,
                                                    int ntiles)
{
    const int ntile = blockIdx.x, img = blockIdx.y, ch = blockIdx.z;
    const int t = threadIdx.x;
    const int N = ntiles * 64;
    __shared__ int wrowS[64];
    const int base = (level * 2 + img) * 256;
    if (t < 64) {
        int n = ntile * 64 + t;
        int dd = n >> lgK, k = n & ((1 << lgK) - 1);
        int wrow = dd * E + gidx[base + k];
        wrowS[t] = wrow;
        if (ch == 0) {
            biasP[img * N + n] = bias[wrow];
            gvP[img * N + n] = gval[base + k];
        }
    }
    __syncthreads();
    const int c = t & 63, r0 = t >> 6;
    const int kk = (ch & 3) * 64 + c;
    const bool lo = ch >= 4;
    _Float16* bp = Bp + ((size_t)(img * ntiles + ntile) * 8 + ch) * 4096;
#pragma unroll
    for (int rr = 0; rr < 64; rr += 4) {
        int r = rr + r0;
        float v = W[(size_t)wrowS[r] * HID + kk];
        _Float16 h = (_Float16)v;
        _Float16 ov = lo ? (_Float16)((v - (float)h) * LO_SCALE) : h;
        bp[r * 64 + (c ^ ((r & 7) << 3))] = ov;
    }
}

// ---------------------------------------------------------------------------
// Mid-layer MFMA GEMM, split-f16 K'=768 (12 logical chunks over 8 stored):
//   acc  += hiA*hiB (ch 0-3)
//   accL += hiA*loB' (ch 4-7) + loA'*hiB (ch 8-11)   [lo' = lo*2048]
//   result = acc + accL/2048
// Tile 64m x 128n, 4 waves (2m x 2n), wave = 32x64 = 2x4 frags of 16x16x32.
// global_load_lds staging (linear dest, pre-swizzled source), swizzled ds_read.
// Epilogue: sin(30*(val+bias))*gv -> S[64][129] -> group reduce -> x_out.
// ---------------------------------------------------------------------------
template <int KGRP>
__global__ __launch_bounds__(256) void mid_mfma_kernel(const _Float16* __restrict__ Ap,
                                                       const _Float16* __restrict__ Bp,
                                                       const float* __restrict__ biasP,
                                                       const float* __restrict__ gvP,
                                                       float* __restrict__ x_out)
{
    const int mt = blockIdx.x, nt = blockIdx.y, img = blockIdx.z;
    const int tid = threadIdx.x;
    const int wave = tid >> 6, lane = tid & 63;
    const int wm = wave & 1, wn = wave >> 1;
    const int l15 = lane & 15, lhi = lane >> 4;

    __shared__ __align__(16) char lds[33088];  // staging 24KB; epilogue S 64x129 f32
    float* S = (float*)lds;

    const int ntiles = gridDim.y * 2;  // N/64
    const int N = ntiles * 64;
    const _Float16* ag = Ap + ((size_t)(img * 16 + mt) * 8) * 4096;
    const _Float16* bg = Bp + ((size_t)(img * ntiles + nt * 2) * 8) * 4096;

    f32x4 acc[2][4], accL[2][4];
#pragma unroll
    for (int mi = 0; mi < 2; mi++)
#pragma unroll
        for (int ni = 0; ni < 4; ni++) { acc[mi][ni] = (f32x4)0.f; accL[mi][ni] = (f32x4)0.f; }

    for (int ch = 0; ch < 12; ++ch) {
        const int sa = (ch < 8) ? (ch & 3) : (ch - 4);  // A: hi,hi,lo'
        const int sb = (ch < 8) ? ch : (ch - 8);        // B: hi,lo',hi
        __syncthreads();
        const _Float16* gaw = ag + sa * 4096;
#pragma unroll
        for (int q = 0; q < 6; ++q) {
            int s = wave * 6 + q;
            const _Float16* g;
            if (s < 8) {
                g = gaw + s * 512 + lane * 8;
            } else {
                int s8 = s - 8;
                g = bg + ((size_t)((s8 >> 3) * 8 + sb)) * 4096 + (s8 & 7) * 512 + lane * 8;
            }
            __builtin_amdgcn_global_load_lds((gvoid*)g, (lvoid*)(lds + s * 1024), 16, 0, 0);
        }
        asm volatile("s_waitcnt vmcnt(0)" ::: "memory");
        __syncthreads();

        f16x8 af[2][2], bf[2][4];
#pragma unroll
        for (int ks = 0; ks < 2; ++ks) {
#pragma unroll
            for (int mi = 0; mi < 2; ++mi) {
                int row = wm * 32 + mi * 16 + l15;
                int slot = (lhi + 4 * ks) ^ (row & 7);
                af[ks][mi] = *(const f16x8*)(lds + row * 128 + slot * 16);
            }
#pragma unroll
            for (int ni = 0; ni < 4; ++ni) {
                int row = wn * 64 + ni * 16 + l15;
                int slot = (lhi + 4 * ks) ^ (row & 7);
                bf[ks][ni] = *(const f16x8*)(lds + 8192 + row * 128 + slot * 16);
            }
        }
        if (ch < 4) {
#pragma unroll
            for (int ks = 0; ks < 2; ++ks)
#pragma unroll
                for (int mi = 0; mi < 2; ++mi)
#pragma unroll
                    for (int ni = 0; ni < 4; ++ni)
                        acc[mi][ni] = __builtin_amdgcn_mfma_f32_16x16x32_f16(af[ks][mi], bf[ks][ni],
                                                                             acc[mi][ni], 0, 0, 0);
        } else {
#pragma unroll
            for (int ks = 0; ks < 2; ++ks)
#pragma unroll
                for (int mi = 0; mi < 2; ++mi)
#pragma unroll
                    for (int ni = 0; ni < 4; ++ni)
                        accL[mi][ni] = __builtin_amdgcn_mfma_f32_16x16x32_f16(af[ks][mi], bf[ks][ni],
                                                                              accL[mi][ni], 0, 0, 0);
        }
    }
    __syncthreads();

    // epilogue: combine hi/lo accumulators, sin + gate weight -> S
#pragma unroll
    for (int mi = 0; mi < 2; ++mi)
#pragma unroll
        for (int ni = 0; ni < 4; ++ni) {
            int n = wn * 64 + ni * 16 + l15;
            int gn = nt * 128 + n;
            float bv = biasP[img * N + gn];
            float gv = gvP[img * N + gn];
#pragma unroll
            for (int r = 0; r < 4; ++r) {
                int m = wm * 32 + mi * 16 + lhi * 4 + r;
                float val = acc[mi][ni][r] + accL[mi][ni][r] * LO_INV;
                S[m * 129 + n] = gv * sinf(30.f * (val + bv));
            }
        }
    __syncthreads();

    float* xo = x_out + ((size_t)img * NC + mt * 64) * HID;
    if (KGRP == 32) {
        int m = tid >> 2, d = tid & 3;
        float s = 0.f;
#pragma unroll
        for (int j = 0; j < 32; ++j) s += S[m * 129 + d * 32 + ((j + d * 8) & 31)];
        xo[m * HID + nt * 4 + d] = s;
    } else {
#pragma unroll
        for (int rep = 0; rep < 8; ++rep) {
            int idx = rep * 256 + tid;
            int m = idx >> 5, d = idx & 31;
            const float* Sp = S + m * 129 + d * 4;
            xo[m * HID + nt * 32 + d] = Sp[0] + Sp[1] + Sp[2] + Sp[3];
        }
    }
}

// ---------------------------------------------------------------------------
// Layer 4 (output): out[i,c,d] = sum_e gv[e]*(W4[d*1024+e,:]·x[i,c,:] + b4)
// ---------------------------------------------------------------------------
__global__ __launch_bounds__(256) void layer4_kernel(const float* __restrict__ x_in,
                                                     const float* __restrict__ W4,
                                                     const float* __restrict__ b4,
                                                     const int* __restrict__ gidx,
                                                     const float* __restrict__ gval,
                                                     float* __restrict__ out)
{
    const int img = blockIdx.y;
    const int c0 = blockIdx.x * 8;
    const int t = threadIdx.x;
    __shared__ float xs[8][256];
    __shared__ float redl[4][24];
    const int base = (4 * 2 + img) * 256;
    const int e = gidx[base + t];
    const float g = gval[base + t];

    const float* xb = x_in + ((size_t)img * NC + c0) * HID;
#pragma unroll
    for (int q = 0; q < 2; q++) {
        int f = t + q * 256;
        int c = f >> 6, j4 = f & 63;
        *(float4*)&xs[c][j4 * 4] = *(const float4*)(xb + c * HID + j4 * 4);
    }
    __syncthreads();

    float acc[3][8];
#pragma unroll
    for (int d = 0; d < 3; d++)
#pragma unroll
        for (int c = 0; c < 8; c++) acc[d][c] = 0.f;

    const float* w0p = W4 + (size_t)(0 * 1024 + e) * 256;
    const float* w1p = W4 + (size_t)(1 * 1024 + e) * 256;
    const float* w2p = W4 + (size_t)(2 * 1024 + e) * 256;
#pragma unroll 2
    for (int j = 0; j < 256; j += 4) {
        const float4 w0 = *(const float4*)(w0p + j);
        const float4 w1 = *(const float4*)(w1p + j);
        const float4 w2 = *(const float4*)(w2p + j);
#pragma unroll
        for (int c = 0; c < 8; c++) {
            const float4 xv = *(const float4*)&xs[c][j];
            acc[0][c] += w0.x * xv.x + w0.y * xv.y + w0.z * xv.z + w0.w * xv.w;
            acc[1][c] += w1.x * xv.x + w1.y * xv.y + w1.z * xv.z + w1.w * xv.w;
            acc[2][c] += w2.x * xv.x + w2.y * xv.y + w2.z * xv.z + w2.w * xv.w;
        }
    }

    float p[24];
#pragma unroll
    for (int d = 0; d < 3; d++) {
        const float bb = b4[d * 1024 + e];
#pragma unroll
        for (int c = 0; c < 8; c++) p[d * 8 + c] = g * (acc[d][c] + bb);
    }
#pragma unroll
    for (int v = 0; v < 24; v++) {
        float x = p[v];
#pragma unroll
        for (int off = 32; off; off >>= 1) x += __shfl_down(x, off);
        p[v] = x;
    }
    if ((t & 63) == 0) {
        int w = t >> 6;
#pragma unroll
        for (int v = 0; v < 24; v++) redl[w][v] = p[v];
    }
    __syncthreads();
    if (t < 24) {
        float s = redl[0][t] + redl[1][t] + redl[2][t] + redl[3][t];
        int d = t / 8, c = t % 8;
        out[((size_t)img * NC + c0 + c) * 3 + d] = s;
    }
}

// ---------------------------------------------------------------------------
extern "C" void kernel_launch(void* const* d_in, const int* in_sizes, int n_in,
                              void* d_out, int out_size, void* d_ws, size_t ws_size,
                              hipStream_t stream)
{
    const float* rg     = (const float*)d_in[0];
    const float* coords = (const float*)d_in[1];
    const float* W0 = (const float*)d_in[2];
    const float* b0 = (const float*)d_in[3];
    const float* W1 = (const float*)d_in[4];
    const float* b1 = (const float*)d_in[5];
    const float* W2 = (const float*)d_in[6];
    const float* b2 = (const float*)d_in[7];
    const float* W3 = (const float*)d_in[8];
    const float* b3 = (const float*)d_in[9];
    const float* W4 = (const float*)d_in[10];
    const float* b4 = (const float*)d_in[11];
    float* out = (float*)d_out;

    char* ws = (char*)d_ws;
    int*      gidx  = (int*)ws;                                // 10240 B
    float*    gval  = (float*)(ws + 10240);                    // 10240 B
    float*    xA    = (float*)(ws + 20480);                    // 2 MiB
    float*    xB    = (float*)(ws + 2117632);                  // 2 MiB
    _Float16* Ap    = (_Float16*)(ws + 4214784);               // 2 MiB
    _Float16* Bp    = (_Float16*)(ws + 6311936);               // 16 MiB
    float*    biasP = (float*)(ws + 23089152);                 // 64 KiB
    float*    gvP   = (float*)(ws + 23154688);                 // 64 KiB

    gate_kernel<<<dim3(5, 2), 1024, 0, stream>>>(rg, gidx, gval);
    layer0_kernel<<<dim3(NC, NI), 256, 0, stream>>>(coords, W0, b0, gidx, gval, xA);

    // level 1: E=16, K=4, N=1024
    xpack_kernel<<<dim3(16, 2, 8), 256, 0, stream>>>(xA, Ap);
    wpack_kernel<<<dim3(16, 2, 8), 256, 0, stream>>>(W1, b1, gidx, gval, 1, 16, 2, Bp, biasP, gvP, 16);
    mid_mfma_kernel<4><<<dim3(16, 8, 2), 256, 0, stream>>>(Ap, Bp, biasP, gvP, xB);

    // level 2: E=64, K=32, N=8192
    xpack_kernel<<<dim3(16, 2, 8), 256, 0, stream>>>(xB, Ap);
    wpack_kernel<<<dim3(128, 2, 8), 256, 0, stream>>>(W2, b2, gidx, gval, 2, 64, 5, Bp, biasP, gvP, 128);
    mid_mfma_kernel<32><<<dim3(16, 64, 2), 256, 0, stream>>>(Ap, Bp, biasP, gvP, xA);

    // level 3: E=256, K=32, N=8192
    xpack_kernel<<<dim3(16, 2, 8), 256, 0, stream>>>(xA, Ap);
    wpack_kernel<<<dim3(128, 2, 8), 256, 0, stream>>>(W3, b3, gidx, gval, 3, 256, 5, Bp, biasP, gvP, 128);
    mid_mfma_kernel<32><<<dim3(16, 64, 2), 256, 0, stream>>>(Ap, Bp, biasP, gvP, xB);

    layer4_kernel<<<dim3(128, NI), 256, 0, stream>>>(xB, W4, b4, gidx, gval, out);
}

// Round 7
// 364.841 us; speedup vs baseline: 1.5387x; 1.1116x over previous
//
#include <hip/hip_runtime.h>
#include <math.h>

#define NC 1024
#define HID 256
#define NI 2

typedef _Float16 f16x8 __attribute__((ext_vector_type(8)));
typedef float f32x4 __attribute__((ext_vector_type(4)));
using gvoid = __attribute__((address_space(1))) const void;
using lvoid = __attribute__((address_space(3))) void;

#define LO_SCALE 2048.0f
#define LO_INV (1.0f / 2048.0f)

// ---------------------------------------------------------------------------
// Top-K gating, thread-per-element (block=1024). rank = #{j : |g_j|>|g_e| or
// (|g_j|==|g_e| and j<e)}; keep rank<K. Matches jax.lax.top_k ordering.
// ---------------------------------------------------------------------------
__global__ __launch_bounds__(1024) void gate_kernel(const float* __restrict__ rg,
                                                    int* __restrict__ gidx,
                                                    float* __restrict__ gval)
{
    const int EDAT[5] = {8, 16, 64, 256, 1024};
    const int KDAT[5] = {4, 4, 32, 32, 256};
    const int OFF[5]  = {0, 8, 24, 88, 344};
    const int level = blockIdx.x, img = blockIdx.y;
    const int E = EDAT[level], K = KDAT[level], off = OFF[level];
    __shared__ float ga[1024];
    const float* src = rg + img * 1368 + off;
    const int t = threadIdx.x;
    if (t < E) ga[t] = src[t];
    __syncthreads();
    if (t < E) {
        const float v = ga[t];
        const float a = fabsf(v);
        int rank = 0;
#pragma unroll 8
        for (int j = 0; j < E; j++) {
            float aj = fabsf(ga[j]);
            rank += (aj > a) || (aj == a && j < t);
        }
        if (rank < K) {
            int base = (level * 2 + img) * 256;
            gidx[base + rank] = t;
            gval[base + rank] = v;
        }
    }
}

// ---------------------------------------------------------------------------
// Layer 0: x[i,c,h] = sum_k gv[k]*sin(30*(coords[c]·W0row + b0))
// ---------------------------------------------------------------------------
__global__ __launch_bounds__(256) void layer0_kernel(const float* __restrict__ coords,
                                                     const float* __restrict__ W0,
                                                     const float* __restrict__ b0,
                                                     const int* __restrict__ gidx,
                                                     const float* __restrict__ gval,
                                                     float* __restrict__ xout)
{
    const int c = blockIdx.x, img = blockIdx.y, h = threadIdx.x;
    __shared__ int gi[4];
    __shared__ float gv[4];
    if (h < 4) {
        int base = (0 * 2 + img) * 256;
        gi[h] = gidx[base + h];
        gv[h] = gval[base + h];
    }
    __syncthreads();
    const float c0 = coords[c * 2], c1 = coords[c * 2 + 1];
    float s = 0.f;
#pragma unroll
    for (int k = 0; k < 4; k++) {
        int row = h * 8 + gi[k];
        s += gv[k] * sinf(30.f * (c0 * W0[row * 2] + c1 * W0[row * 2 + 1] + b0[row]));
    }
    xout[((size_t)img * NC + c) * HID + h] = s;
}

// ---------------------------------------------------------------------------
// x-pack: f32 x -> Ap f16 [img][16 mt][8 planes][64x64 swz]; planes 0-3 hi,
// 4-7 lo*2048. One block per (mt,img,sa) writes BOTH hi and lo (single read).
// ---------------------------------------------------------------------------
__global__ __launch_bounds__(256) void xpack_kernel(const float* __restrict__ x,
                                                    _Float16* __restrict__ Ap)
{
    const int mt = blockIdx.x, img = blockIdx.y, sa = blockIdx.z;  // sa 0..3
    const int t = threadIdx.x;
    const int c = t & 63, r0 = t >> 6;
    const float* xb = x + ((size_t)img * NC + mt * 64) * HID;
    _Float16* aph = Ap + ((size_t)(img * 16 + mt) * 8 + sa) * 4096;
    _Float16* apl = aph + 4 * 4096;
    const int kk = sa * 64 + c;
#pragma unroll
    for (int rr = 0; rr < 64; rr += 4) {
        int r = rr + r0;
        float v = xb[r * HID + kk];
        _Float16 h = (_Float16)v;
        int idx = r * 64 + (c ^ ((r & 7) << 3));
        aph[idx] = h;
        apl[idx] = (_Float16)((v - (float)h) * LO_SCALE);
    }
}

// ---------------------------------------------------------------------------
// W-pack: gather active rows (per img), hi+lo planes in one pass.
// Bp layout [img][ntile(64 rows)][8 planes][4096]; 0-3 hi, 4-7 lo*2048.
// biasP/gvP written by sa==0 blocks.
// ---------------------------------------------------------------------------
__global__ __launch_bounds__(256) void wpack_kernel(const float* __restrict__ W,
                                                    const float* __restrict__ bias,
                                                    const int* __restrict__ gidx,
                                                    const float* __restrict__ gval,
                                                    int level, int E, int lgK,
                                                    _Float16* __restrict__ Bp,
                                                    float* __restrict__ biasP,
                                                    float* __restrict__ gvP,
                                                    int ntiles)
{
    const int ntile = blockIdx.x, img = blockIdx.y, sa = blockIdx.z;  // sa 0..3
    const int t = threadIdx.x;
    const int N = ntiles * 64;
    __shared__ int wrowS[64];
    const int base = (level * 2 + img) * 256;
    if (t < 64) {
        int n = ntile * 64 + t;
        int dd = n >> lgK, k = n & ((1 << lgK) - 1);
        int wrow = dd * E + gidx[base + k];
        wrowS[t] = wrow;
        if (sa == 0) {
            biasP[img * N + n] = bias[wrow];
            gvP[img * N + n] = gval[base + k];
        }
    }
    __syncthreads();
    const int c = t & 63, r0 = t >> 6;
    const int kk = sa * 64 + c;
    _Float16* bph = Bp + ((size_t)(img * ntiles + ntile) * 8 + sa) * 4096;
    _Float16* bpl = bph + 4 * 4096;
#pragma unroll
    for (int rr = 0; rr < 64; rr += 4) {
        int r = rr + r0;
        float v = W[(size_t)wrowS[r] * HID + kk];
        _Float16 h = (_Float16)v;
        int idx = r * 64 + (c ^ ((r & 7) << 3));
        bph[idx] = h;
        bpl[idx] = (_Float16)((v - (float)h) * LO_SCALE);
    }
}

// ---------------------------------------------------------------------------
// Mid-layer MFMA GEMM, split-f16, XCD-swizzled flat grid, double-buffered LDS.
//   acc  += hiA*hiB (ch 0-3);  accL += hiA*loB' (4-7) + loA'*hiB (8-11)
//   result = acc + accL/2048
// Flat block id b: q=b&7 (XCD), j=b>>3: mt=j&15, img=(j>>4)&1, nt=q*NNTX+(j>>5)
// -> each XCD owns an nt-stripe; A(2MiB)+B-stripe(2MiB) fit its 4MiB L2.
// Per iter: vmcnt(0); barrier; stage(next chunk, other buffer); ds_read+MFMA.
// ---------------------------------------------------------------------------
template <int KGRP, int NNT>
__global__ __launch_bounds__(256) void mid_mfma_kernel(const _Float16* __restrict__ Ap,
                                                       const _Float16* __restrict__ Bp,
                                                       const float* __restrict__ biasP,
                                                       const float* __restrict__ gvP,
                                                       float* __restrict__ x_out)
{
    static_assert(NNT % 8 == 0 || NNT == 8, "NNT multiple of 8");
    constexpr int NNTX = NNT / 8;
    const int b = blockIdx.x;
    const int q = b & 7;
    const int j = b >> 3;
    const int mt = j & 15;
    const int img = (j >> 4) & 1;
    const int nt = q * NNTX + (j >> 5);

    const int tid = threadIdx.x;
    const int wave = tid >> 6, lane = tid & 63;
    const int wm = wave & 1, wn = wave >> 1;
    const int l15 = lane & 15, lhi = lane >> 4;

    __shared__ __align__(16) char lds[49152];  // 2 x 24KB staging; S (33KB) aliases
    float* S = (float*)lds;

    const int ntiles = NNT * 2;
    const int N = ntiles * 64;
    const _Float16* ag = Ap + ((size_t)(img * 16 + mt) * 8) * 4096;
    const _Float16* bg = Bp + ((size_t)(img * ntiles + nt * 2) * 8) * 4096;

    auto stage = [&](int off, int ch) {
        const int sa = (ch < 8) ? (ch & 3) : (ch - 4);  // A: hi,hi,lo'
        const int sb = (ch < 8) ? ch : (ch - 8);        // B: hi,lo',hi
        const _Float16* gaw = ag + sa * 4096;
#pragma unroll
        for (int q6 = 0; q6 < 6; ++q6) {
            int s = wave * 6 + q6;
            const _Float16* g;
            if (s < 8) {
                g = gaw + s * 512 + lane * 8;
            } else {
                int s8 = s - 8;
                g = bg + ((size_t)((s8 >> 3) * 8 + sb)) * 4096 + (s8 & 7) * 512 + lane * 8;
            }
            __builtin_amdgcn_global_load_lds((gvoid*)g, (lvoid*)(lds + off + s * 1024), 16, 0, 0);
        }
    };

    f32x4 acc[2][4], accL[2][4];
#pragma unroll
    for (int mi = 0; mi < 2; mi++)
#pragma unroll
        for (int ni = 0; ni < 4; ni++) { acc[mi][ni] = (f32x4)0.f; accL[mi][ni] = (f32x4)0.f; }

    stage(0, 0);  // prologue

    for (int ch = 0; ch < 12; ++ch) {
        const int cur = (ch & 1) * 24576;
        asm volatile("s_waitcnt vmcnt(0)" ::: "memory");
        __syncthreads();                       // chunk ch landed; prev readers done
        if (ch < 11) stage(24576 - cur, ch + 1);  // early-issue next chunk

        f16x8 af[2][2], bf[2][4];
#pragma unroll
        for (int ks = 0; ks < 2; ++ks) {
#pragma unroll
            for (int mi = 0; mi < 2; ++mi) {
                int row = wm * 32 + mi * 16 + l15;
                int slot = (lhi + 4 * ks) ^ (row & 7);
                af[ks][mi] = *(const f16x8*)(lds + cur + row * 128 + slot * 16);
            }
#pragma unroll
            for (int ni = 0; ni < 4; ++ni) {
                int row = wn * 64 + ni * 16 + l15;
                int slot = (lhi + 4 * ks) ^ (row & 7);
                bf[ks][ni] = *(const f16x8*)(lds + cur + 8192 + row * 128 + slot * 16);
            }
        }
        if (ch < 4) {
#pragma unroll
            for (int ks = 0; ks < 2; ++ks)
#pragma unroll
                for (int mi = 0; mi < 2; ++mi)
#pragma unroll
                    for (int ni = 0; ni < 4; ++ni)
                        acc[mi][ni] = __builtin_amdgcn_mfma_f32_16x16x32_f16(af[ks][mi], bf[ks][ni],
                                                                             acc[mi][ni], 0, 0, 0);
        } else {
#pragma unroll
            for (int ks = 0; ks < 2; ++ks)
#pragma unroll
                for (int mi = 0; mi < 2; ++mi)
#pragma unroll
                    for (int ni = 0; ni < 4; ++ni)
                        accL[mi][ni] = __builtin_amdgcn_mfma_f32_16x16x32_f16(af[ks][mi], bf[ks][ni],
                                                                              accL[mi][ni], 0, 0, 0);
        }
    }
    __syncthreads();

    // epilogue: combine hi/lo accumulators, sin + gate weight -> S
#pragma unroll
    for (int mi = 0; mi < 2; ++mi)
#pragma unroll
        for (int ni = 0; ni < 4; ++ni) {
            int n = wn * 64 + ni * 16 + l15;
            int gn = nt * 128 + n;
            float bv = biasP[img * N + gn];
            float gv = gvP[img * N + gn];
#pragma unroll
            for (int r = 0; r < 4; ++r) {
                int m = wm * 32 + mi * 16 + lhi * 4 + r;
                float val = acc[mi][ni][r] + accL[mi][ni][r] * LO_INV;
                S[m * 129 + n] = gv * sinf(30.f * (val + bv));
            }
        }
    __syncthreads();

    float* xo = x_out + ((size_t)img * NC + mt * 64) * HID;
    if (KGRP == 32) {
        int m = tid >> 2, d = tid & 3;
        float s = 0.f;
#pragma unroll
        for (int jj = 0; jj < 32; ++jj) s += S[m * 129 + d * 32 + ((jj + d * 8) & 31)];
        xo[m * HID + nt * 4 + d] = s;
    } else {
#pragma unroll
        for (int rep = 0; rep < 8; ++rep) {
            int idx = rep * 256 + tid;
            int m = idx >> 5, d = idx & 31;
            const float* Sp = S + m * 129 + d * 4;
            xo[m * HID + nt * 32 + d] = Sp[0] + Sp[1] + Sp[2] + Sp[3];
        }
    }
}

// ---------------------------------------------------------------------------
// Layer 4 precombine: gates are applied linearly, so fold them into weights:
//   Weff[i,d,:] = sum_e gv[e]*W4[d*1024+gidx[e],:],  beff[i,d] = sum_e gv[e]*b4
// ---------------------------------------------------------------------------
__global__ __launch_bounds__(256) void l4combine_kernel(const float* __restrict__ W4,
                                                        const float* __restrict__ b4,
                                                        const int* __restrict__ gidx,
                                                        const float* __restrict__ gval,
                                                        float* __restrict__ Weff,
                                                        float* __restrict__ beff)
{
    const int d = blockIdx.x, img = blockIdx.y;
    const int t = threadIdx.x;
    const int base = (4 * 2 + img) * 256;
    __shared__ int rows[256];
    __shared__ float gs[256];
    __shared__ float bred[256];
    int e = gidx[base + t];
    float g = gval[base + t];
    rows[t] = (d * 1024 + e) * 256;
    gs[t] = g;
    bred[t] = g * b4[d * 1024 + e];
    __syncthreads();
    float acc = 0.f;
#pragma unroll 4
    for (int k = 0; k < 256; ++k)
        acc = fmaf(gs[k], W4[(size_t)rows[k] + t], acc);
    Weff[(img * 3 + d) * 256 + t] = acc;
    for (int s = 128; s > 0; s >>= 1) {
        if (t < s) bred[t] += bred[t + s];
        __syncthreads();
    }
    if (t == 0) beff[img * 3 + d] = bred[0];
}

// ---------------------------------------------------------------------------
// Layer 4 apply: out[i,c,d] = x[i,c,:]·Weff[i,d,:] + beff[i,d]
// ---------------------------------------------------------------------------
__global__ __launch_bounds__(256) void l4apply_kernel(const float* __restrict__ x_in,
                                                      const float* __restrict__ Weff,
                                                      const float* __restrict__ beff,
                                                      float* __restrict__ out)
{
    const int img = blockIdx.y;
    const int c = blockIdx.x * 256 + threadIdx.x;
    __shared__ float ws[3][256];
    __shared__ float bs[3];
    const int t = threadIdx.x;
    if (t < 192) {
        int d = t / 64, k4 = t % 64;
        *(float4*)&ws[d][k4 * 4] = *(const float4*)(Weff + (img * 3 + d) * 256 + k4 * 4);
    }
    if (t < 3) bs[t] = beff[img * 3 + t];
    __syncthreads();
    const float* xb = x_in + ((size_t)img * NC + c) * HID;
    float a0 = 0.f, a1 = 0.f, a2 = 0.f;
#pragma unroll 4
    for (int k = 0; k < 256; k += 4) {
        const float4 xv = *(const float4*)(xb + k);
        const float4 w0 = *(const float4*)&ws[0][k];
        const float4 w1 = *(const float4*)&ws[1][k];
        const float4 w2 = *(const float4*)&ws[2][k];
        a0 += xv.x * w0.x + xv.y * w0.y + xv.z * w0.z + xv.w * w0.w;
        a1 += xv.x * w1.x + xv.y * w1.y + xv.z * w1.z + xv.w * w1.w;
        a2 += xv.x * w2.x + xv.y * w2.y + xv.z * w2.z + xv.w * w2.w;
    }
    float* o = out + ((size_t)img * NC + c) * 3;
    o[0] = a0 + bs[0];
    o[1] = a1 + bs[1];
    o[2] = a2 + bs[2];
}

// ---------------------------------------------------------------------------
extern "C" void kernel_launch(void* const* d_in, const int* in_sizes, int n_in,
                              void* d_out, int out_size, void* d_ws, size_t ws_size,
                              hipStream_t stream)
{
    const float* rg     = (const float*)d_in[0];
    const float* coords = (const float*)d_in[1];
    const float* W0 = (const float*)d_in[2];
    const float* b0 = (const float*)d_in[3];
    const float* W1 = (const float*)d_in[4];
    const float* b1 = (const float*)d_in[5];
    const float* W2 = (const float*)d_in[6];
    const float* b2 = (const float*)d_in[7];
    const float* W3 = (const float*)d_in[8];
    const float* b3 = (const float*)d_in[9];
    const float* W4 = (const float*)d_in[10];
    const float* b4 = (const float*)d_in[11];
    float* out = (float*)d_out;

    char* ws = (char*)d_ws;
    int*      gidx  = (int*)ws;                                // 10240 B
    float*    gval  = (float*)(ws + 10240);                    // 10240 B
    float*    xA    = (float*)(ws + 20480);                    // 2 MiB
    float*    xB    = (float*)(ws + 2117632);                  // 2 MiB
    _Float16* Ap    = (_Float16*)(ws + 4214784);               // 2 MiB
    _Float16* Bp    = (_Float16*)(ws + 6311936);               // 16 MiB
    float*    biasP = (float*)(ws + 23089152);                 // 64 KiB
    float*    gvP   = (float*)(ws + 23154688);                 // 64 KiB
    float*    Weff  = (float*)(ws + 23220224);                 // 6 KiB
    float*    beff  = (float*)(ws + 23228416);                 // 24 B

    gate_kernel<<<dim3(5, 2), 1024, 0, stream>>>(rg, gidx, gval);
    l4combine_kernel<<<dim3(3, 2), 256, 0, stream>>>(W4, b4, gidx, gval, Weff, beff);
    layer0_kernel<<<dim3(NC, NI), 256, 0, stream>>>(coords, W0, b0, gidx, gval, xA);

    // level 1: E=16, K=4, N=1024 (8 nt blocks)
    xpack_kernel<<<dim3(16, 2, 4), 256, 0, stream>>>(xA, Ap);
    wpack_kernel<<<dim3(16, 2, 4), 256, 0, stream>>>(W1, b1, gidx, gval, 1, 16, 2, Bp, biasP, gvP, 16);
    mid_mfma_kernel<4, 8><<<256, 256, 0, stream>>>(Ap, Bp, biasP, gvP, xB);

    // level 2: E=64, K=32, N=8192 (64 nt blocks)
    xpack_kernel<<<dim3(16, 2, 4), 256, 0, stream>>>(xB, Ap);
    wpack_kernel<<<dim3(128, 2, 4), 256, 0, stream>>>(W2, b2, gidx, gval, 2, 64, 5, Bp, biasP, gvP, 128);
    mid_mfma_kernel<32, 64><<<2048, 256, 0, stream>>>(Ap, Bp, biasP, gvP, xA);

    // level 3: E=256, K=32, N=8192
    xpack_kernel<<<dim3(16, 2, 4), 256, 0, stream>>>(xA, Ap);
    wpack_kernel<<<dim3(128, 2, 4), 256, 0, stream>>>(W3, b3, gidx, gval, 3, 256, 5, Bp, biasP, gvP, 128);
    mid_mfma_kernel<32, 64><<<2048, 256, 0, stream>>>(Ap, Bp, biasP, gvP, xB);

    l4apply_kernel<<<dim3(4, 2), 256, 0, stream>>>(xB, Weff, beff, out);
}